// Round 2
// baseline (6246.349 us; speedup 1.0000x reference)
//
#include <hip/hip_runtime.h>
#include <cmath>

#define B_ 256
#define F_ 2048
#define T_ 40
#define V_ 10000
#define L_ 20
#define ATTR_ 400
#define E_ 512
#define H_ 1024
#define A_ 512
#define NS_ 19

typedef float f32x4 __attribute__((ext_vector_type(4)));
typedef short bf16x8 __attribute__((ext_vector_type(8)));

__device__ __forceinline__ float sigm(float x) { return 1.0f / (1.0f + expf(-x)); }

// split-bf16 helpers: x ~= hi + lo, each bf16 (RNE). residual ~2^-18 * |x|
__device__ __forceinline__ unsigned short f2bf(float x) {
    unsigned int u = __float_as_uint(x);
    u += 0x7fffu + ((u >> 16) & 1u);
    return (unsigned short)(u >> 16);
}
__device__ __forceinline__ float bf2f(unsigned short h) {
    return __uint_as_float(((unsigned int)h) << 16);
}
__device__ __forceinline__ void gload16(const void* g, void* l) {
    __builtin_amdgcn_global_load_lds(
        (const __attribute__((address_space(1))) unsigned int*)g,
        (__attribute__((address_space(3))) unsigned int*)l, 16, 0, 0);
}
__device__ __forceinline__ f32x4 mfma16(bf16x8 a, bf16x8 b, f32x4 c) {
    return __builtin_amdgcn_mfma_f32_16x16x32_bf16(a, b, c, 0, 0, 0);
}

// ---------------------------------------------------------------------------
// Split-bf16 MFMA GEMM, 2-phase double-buffered.
// C[b][m] = sum_k A[m][k]*B[b][k], A/B row-major k-contiguous bf16 hi/lo.
// Tile 128m x 256n, 512 threads (8 waves in 2m x 4n grid), per-wave 64x64 via
// 4x4 frags of v_mfma_f32_16x16x32_bf16 (hh + hl + lh products).
// blockIdx.z = independent K-chunk; partials -> out + z*zstride (DIRECT=0)
// or direct store with bias[m] (DIRECT=1).
// LDS: 2 x 48 slabs x 1KB = 96 KB. Slab = [kg4][row16][8elem] (linear for
// both global_load_lds and ds_read_b128 -> conflict-free).
// K-loop: stage(t^1, ks+1) issued BEFORE compute of tile t; single barrier
// per iteration drains the prefetch after ~500cy of MFMA has hidden it.
// ---------------------------------------------------------------------------
struct GChunk {
    const unsigned short* Ahi; const unsigned short* Alo;
    const unsigned short* Bhi; const unsigned short* Blo;
    int lda, ldb, kc;
};
struct GChunks { GChunk c[8]; };

template<int DIRECT>
__global__ __launch_bounds__(512) void gemm_mfma(
    GChunks ch, float* __restrict__ out, const float* __restrict__ bias,
    int Mreal, long ldc, long zstride)
{
    const GChunk cc = ch.c[blockIdx.z];
    const int tid  = threadIdx.x;
    const int lane = tid & 63;
    const int w    = tid >> 6;           // 0..7
    const int m0   = blockIdx.x * 128;
    const int n0   = blockIdx.y * 256;
    const int kg   = lane >> 4;
    const int rr   = lane & 15;

    // 2 bufs x 48 slabs x 512 shorts: A-hi 0..7, A-lo 8..15, B-hi 16..31, B-lo 32..47
    __shared__ __align__(16) unsigned short lds[2][48][512];

    // each wave stages 6 slabs: s = w*6 + q
    const unsigned short* gptr[6];
#pragma unroll
    for (int q = 0; q < 6; ++q) {
        int s = w * 6 + q;
        if (s < 16) {                       // A slab
            int p  = s >> 3;
            int ms = s & 7;
            int row = m0 + ms * 16 + rr;
            if (row >= Mreal) row = Mreal - 1;
            const unsigned short* base = p ? cc.Alo : cc.Ahi;
            gptr[q] = base + (long)row * cc.lda + kg * 8;
        } else {                            // B slab
            int t2 = s - 16;
            int p  = t2 >> 4;
            int ns = t2 & 15;
            int row = n0 + ns * 16 + rr;
            const unsigned short* base = p ? cc.Blo : cc.Bhi;
            gptr[q] = base + (long)row * cc.ldb + kg * 8;
        }
    }

    auto stage = [&](int t) {
#pragma unroll
        for (int q = 0; q < 6; ++q) {
            gload16(gptr[q], &lds[t][w * 6 + q][lane * 8]);
            gptr[q] += 32;
        }
    };

    f32x4 zero4 = {0.f, 0.f, 0.f, 0.f};
    f32x4 acc[4][4];
#pragma unroll
    for (int i = 0; i < 4; ++i)
#pragma unroll
        for (int j = 0; j < 4; ++j) acc[i][j] = zero4;

    const int ms0 = (w >> 2) * 4;     // wave's A slab base (0 or 4)
    const int ns0 = (w & 3) * 4;      // wave's B slab base (0,4,8,12)

    const int kst = cc.kc >> 5;
    stage(0);
    __syncthreads();
    int t = 0;
    for (int ks = 0; ks < kst; ++ks) {
        if (ks + 1 < kst) stage(t ^ 1);     // prefetch next tile (overlaps MFMA)
        bf16x8 ah[4], al[4], bh[4], bl[4];
#pragma unroll
        for (int i = 0; i < 4; ++i) {
            ah[i] = *(const bf16x8*)&lds[t][ms0 + i][lane * 8];
            al[i] = *(const bf16x8*)&lds[t][8 + ms0 + i][lane * 8];
            bh[i] = *(const bf16x8*)&lds[t][16 + ns0 + i][lane * 8];
            bl[i] = *(const bf16x8*)&lds[t][32 + ns0 + i][lane * 8];
        }
#pragma unroll
        for (int i = 0; i < 4; ++i)
#pragma unroll
            for (int j = 0; j < 4; ++j) {
                acc[i][j] = mfma16(ah[i], bh[j], acc[i][j]);
                acc[i][j] = mfma16(ah[i], bl[j], acc[i][j]);
                acc[i][j] = mfma16(al[i], bh[j], acc[i][j]);
            }
        __syncthreads();   // drains prefetch vmcnt + all lds reads of buf t
        t ^= 1;
    }

    const int wm = (w >> 2) * 64;
    const int wn = (w & 3) * 64;
    const int mr = (lane >> 4) * 4;
    const int ncl = lane & 15;
    float* P = DIRECT ? out : out + (long)blockIdx.z * zstride;
#pragma unroll
    for (int i = 0; i < 4; ++i) {
        int mm = m0 + wm + i * 16 + mr;
        if (mm < Mreal) {
            float4 bv = {0.f, 0.f, 0.f, 0.f};
            if (DIRECT && bias) bv = *(const float4*)&bias[mm];
#pragma unroll
            for (int j = 0; j < 4; ++j) {
                int bb = n0 + wn + j * 16 + ncl;
                float4 v;
                v.x = acc[i][j].x + bv.x;
                v.y = acc[i][j].y + bv.y;
                v.z = acc[i][j].z + bv.z;
                v.w = acc[i][j].w + bv.w;
                *(float4*)&P[(long)bb * ldc + mm] = v;
            }
        }
    }
}

// fused split-K reduce + LSTM elementwise.  P layout [z][b][4096] (i|f|g|o).
// bmode 1: base[b][4096] (precomputed mean-feature term incl. biases)
// bmode 2: base[n] broadcast bias vector
__global__ __launch_bounds__(256) void lstm_fused(
    const float* __restrict__ P, int nz, long zstride,
    const float* __restrict__ base, int bmode,
    float* __restrict__ c,
    unsigned short* __restrict__ hhi, unsigned short* __restrict__ hlo)
{
    int idx = blockIdx.x * 256 + threadIdx.x;
    int n = idx & 1023;
    long r = ((long)(idx >> 10)) * 4096 + n;
    float ig = 0.f, fg = 0.f, gg = 0.f, og = 0.f;
    for (int z = 0; z < nz; ++z) {
        const float* p = P + (long)z * zstride + r;
        ig += p[0]; fg += p[1024]; gg += p[2048]; og += p[3072];
    }
    if (bmode == 1) {
        const float* q = base + r;
        ig += q[0]; fg += q[1024]; gg += q[2048]; og += q[3072];
    } else {
        ig += base[n]; fg += base[1024 + n]; gg += base[2048 + n]; og += base[3072 + n];
    }
    float cn = sigm(fg) * c[idx] + sigm(ig) * tanhf(gg);
    c[idx] = cn;
    float hv = sigm(og) * tanhf(cn);
    unsigned short hi = f2bf(hv);
    hhi[idx] = hi;
    hlo[idx] = f2bf(hv - bf2f(hi));
}

// fused attention: eh split-K reduce -> scores -> softmax -> v_hat (-> hi/lo)
__global__ __launch_bounds__(256) void attention_kernel(
    const float* __restrict__ ef, const float* __restrict__ Pe,
    const float* __restrict__ feats, const float* __restrict__ atta_W,
    const float* __restrict__ atta_b,
    unsigned short* __restrict__ vhhi, unsigned short* __restrict__ vhlo)
{
    __shared__ float eh_s[512], aw_s[512], sc_s[48];
    int b = blockIdx.x, tid = threadIdx.x;
    float e0 = 0.f, e1 = 0.f;
#pragma unroll
    for (int z = 0; z < 8; ++z) {
        const float* p = Pe + (long)z * (512 * 256) + b * 512;
        e0 += p[tid]; e1 += p[tid + 256];
    }
    eh_s[tid] = e0; eh_s[tid + 256] = e1;
    aw_s[tid] = atta_W[tid]; aw_s[tid + 256] = atta_W[tid + 256];
    __syncthreads();
    int w = tid >> 6, lane = tid & 63;
    float ab0 = atta_b[0];
    for (int i = 0; i < 10; ++i) {
        int t = w * 10 + i;
        const float* ep = ef + ((long)b * T_ + t) * A_ + lane * 8;
        float4 e1v = *(const float4*)ep;
        float4 e2v = *(const float4*)(ep + 4);
        int a = lane * 8;
        float s = tanhf(e1v.x + eh_s[a+0]) * aw_s[a+0] + tanhf(e1v.y + eh_s[a+1]) * aw_s[a+1]
                + tanhf(e1v.z + eh_s[a+2]) * aw_s[a+2] + tanhf(e1v.w + eh_s[a+3]) * aw_s[a+3]
                + tanhf(e2v.x + eh_s[a+4]) * aw_s[a+4] + tanhf(e2v.y + eh_s[a+5]) * aw_s[a+5]
                + tanhf(e2v.z + eh_s[a+6]) * aw_s[a+6] + tanhf(e2v.w + eh_s[a+7]) * aw_s[a+7];
#pragma unroll
        for (int o = 32; o > 0; o >>= 1) s += __shfl_down(s, o, 64);
        if (lane == 0) sc_s[t] = s + ab0;
    }
    __syncthreads();
    if (tid < 64) {
        float v = (tid < T_) ? sc_s[tid] : -INFINITY;
        float m = v;
#pragma unroll
        for (int o = 32; o > 0; o >>= 1) m = fmaxf(m, __shfl_down(m, o, 64));
        m = __shfl(m, 0, 64);
        float e = (tid < T_) ? expf(v - m) : 0.f;
        float su = e;
#pragma unroll
        for (int o = 32; o > 0; o >>= 1) su += __shfl_down(su, o, 64);
        su = __shfl(su, 0, 64);
        if (tid < T_) sc_s[tid] = e / su;
    }
    __syncthreads();
    for (int cc = 0; cc < 8; ++cc) {
        int f = cc * 256 + tid;
        const float* fp = feats + ((long)b * F_ + f) * T_;
        float acc = 0.f;
#pragma unroll
        for (int t4 = 0; t4 < 10; ++t4) {
            float4 v = *(const float4*)(fp + t4 * 4);
            acc += sc_s[t4*4+0] * v.x + sc_s[t4*4+1] * v.y
                 + sc_s[t4*4+2] * v.z + sc_s[t4*4+3] * v.w;
        }
        unsigned short hi = f2bf(acc);
        vhhi[(long)b * F_ + f] = hi;
        vhlo[(long)b * F_ + f] = f2bf(acc - bf2f(hi));
    }
}

// out[e] = sum_z P[z*zstride+e] + base[e & mask]
__global__ void reduce_rows(float* __restrict__ out, const float* __restrict__ P,
                            const float* __restrict__ base, int S, long zstride,
                            int n, int mask)
{
    long e = ((long)blockIdx.x * 256 + threadIdx.x) * 4;
    if (e >= n) return;
    float4 s = *(const float4*)&P[e];
    for (int z = 1; z < S; ++z) {
        float4 p = *(const float4*)&P[(long)z * zstride + e];
        s.x += p.x; s.y += p.y; s.z += p.z; s.w += p.w;
    }
    if (base) {
        float4 bv = *(const float4*)&base[e & mask];
        s.x += bv.x; s.y += bv.y; s.z += bv.z; s.w += bv.w;
    }
    *(float4*)&out[e] = s;
}

// cast fp32 slice -> bf16 hi/lo, with optional zero-padded columns
__global__ void cast_slice(const float* __restrict__ src,
    unsigned short* __restrict__ dhi, unsigned short* __restrict__ dlo,
    int srcld, int scol0, int nvalid, int nwrite, int dld, int dcol0)
{
    int col = blockIdx.x * 256 + threadIdx.x;
    if (col >= nwrite) return;
    long row = blockIdx.y;
    float v = (col < nvalid) ? src[row * srcld + scol0 + col] : 0.f;
    unsigned short hi = f2bf(v);
    long o = row * dld + dcol0 + col;
    dhi[o] = hi; dlo[o] = f2bf(v - bf2f(hi));
}

__global__ void mean_cast(const float* __restrict__ feats,
                          unsigned short* __restrict__ mh, unsigned short* __restrict__ ml)
{
    int idx = blockIdx.x * 256 + threadIdx.x;
    const float* p = feats + (long)idx * T_;
    float s = 0.f;
#pragma unroll
    for (int t = 0; t < T_; t += 4) {
        float4 v = *(const float4*)(p + t);
        s += v.x + v.y + v.z + v.w;
    }
    s *= (1.0f / (float)T_);
    unsigned short hi = f2bf(s);
    mh[idx] = hi; ml[idx] = f2bf(s - bf2f(hi));
}

// feats[b][f][t] -> featsT[(b*40+t)][f] bf16 hi/lo
__global__ __launch_bounds__(256) void transpose_cast_feats(
    const float* __restrict__ feats,
    unsigned short* __restrict__ fh, unsigned short* __restrict__ fl)
{
    __shared__ float tf[2560];
    int b = blockIdx.y, f0 = blockIdx.x * 64;
    const float* src = feats + (long)b * (F_ * T_) + (long)f0 * T_;
#pragma unroll
    for (int q = 0; q < 10; ++q) tf[q * 256 + threadIdx.x] = src[q * 256 + threadIdx.x];
    __syncthreads();
#pragma unroll
    for (int q = 0; q < 10; ++q) {
        int idx = q * 256 + threadIdx.x;
        int t = idx >> 6, f = idx & 63;
        float v = tf[f * 40 + t];
        unsigned short hi = f2bf(v);
        long o = ((long)b * T_ + t) * F_ + f0 + f;
        fh[o] = hi; fl[o] = f2bf(v - bf2f(hi));
    }
}

__global__ void wv_gather_cast(const int* __restrict__ sents, const float* __restrict__ emb,
    unsigned short* __restrict__ wh, unsigned short* __restrict__ wl, int s)
{
    int idx = blockIdx.x * 256 + threadIdx.x;   // b*512 + e
    int b = idx >> 9, e = idx & 511;
    int wd = sents[b * L_ + s];
    float v = emb[(long)wd * E_ + e];
    unsigned short hi = f2bf(v);
    wh[idx] = hi; wl[idx] = f2bf(v - bf2f(hi));
}

__global__ void vec_add_kernel(const float* a, const float* b, float* out, int n)
{
    int i = blockIdx.x * 256 + threadIdx.x;
    if (i < n) out[i] = a[i] + b[i];
}

__global__ __launch_bounds__(256) void argmax_kernel(
    const float* __restrict__ dout_preds, float* __restrict__ outw, int s)
{
    __shared__ float sv[256];
    __shared__ int   si[256];
    int b = blockIdx.x, tid = threadIdx.x;
    const float* row = dout_preds + (long)b * (NS_ * (long)V_) + (long)s * V_;
    float best = -INFINITY; int bi = 0x7fffffff;
    for (int v = tid; v < V_; v += 256) {
        float x = row[v];
        if (x > best) { best = x; bi = v; }
    }
    sv[tid] = best; si[tid] = bi;
    __syncthreads();
    for (int o = 128; o > 0; o >>= 1) {
        if (tid < o) {
            float ov = sv[tid + o]; int oi = si[tid + o];
            if (ov > sv[tid] || (ov == sv[tid] && oi < si[tid])) { sv[tid] = ov; si[tid] = oi; }
        }
        __syncthreads();
    }
    if (tid == 0) outw[b * NS_ + s] = (float)si[0];
}

extern "C" void kernel_launch(void* const* d_in, const int* in_sizes, int n_in,
                              void* d_out, int out_size, void* d_ws, size_t ws_size,
                              hipStream_t stream)
{
    (void)in_sizes; (void)n_in; (void)out_size; (void)ws_size;
    const float* feats  = (const float*)d_in[0];
    const float* atts   = (const float*)d_in[1];
    const int*   sents  = (const int*)d_in[2];
    const float* attr_W = (const float*)d_in[3];
    const float* attr_b = (const float*)d_in[4];
    const float* emb    = (const float*)d_in[5];
    const float* l1_Wih = (const float*)d_in[6];
    const float* l1_Whh = (const float*)d_in[7];
    const float* l1_bih = (const float*)d_in[8];
    const float* l1_bhh = (const float*)d_in[9];
    const float* l2_Wih = (const float*)d_in[10];
    const float* l2_Whh = (const float*)d_in[11];
    const float* l2_bih = (const float*)d_in[12];
    const float* l2_bhh = (const float*)d_in[13];
    const float* prob_W = (const float*)d_in[14];
    const float* prob_b = (const float*)d_in[15];
    const float* attf_W = (const float*)d_in[16];
    const float* attf_b = (const float*)d_in[17];
    const float* atth_W = (const float*)d_in[18];
    const float* atth_b = (const float*)d_in[19];
    const float* atta_W = (const float*)d_in[20];
    const float* atta_b = (const float*)d_in[21];

    float* out = (float*)d_out;
    float* preds = out + B_ * NS_;

    char* pp = (char*)d_ws;
    auto alloc = [&](size_t n) { char* r = pp; pp += (n + 255) & ~(size_t)255; return r; };

    // region R: featsT (precompute only) overlaid later by W2ih + W1ih-mid
    char* R = alloc(83886080UL);
    unsigned short* fTh   = (unsigned short*)R;
    unsigned short* fTl   = (unsigned short*)(R + 41943040UL);
    unsigned short* W2ihh = (unsigned short*)R;
    unsigned short* W2ihl = (unsigned short*)(R + 25165824UL);
    unsigned short* Wmh   = (unsigned short*)(R + 50331648UL);
    unsigned short* Wml   = (unsigned short*)(R + 67108864UL);

    unsigned short* W1ph  = (unsigned short*)alloc(4096L*1536*2);  // Wih cols [0:1024)++[3072:3584)
    unsigned short* W1pl  = (unsigned short*)alloc(4096L*1536*2);
    unsigned short* W1hhh = (unsigned short*)alloc(4096L*1024*2);
    unsigned short* W1hhl = (unsigned short*)alloc(4096L*1024*2);
    unsigned short* W2hhh = (unsigned short*)alloc(4096L*1024*2);
    unsigned short* W2hhl = (unsigned short*)alloc(4096L*1024*2);
    unsigned short* Wprh  = (unsigned short*)alloc(10000L*1024*2);
    unsigned short* Wprl  = (unsigned short*)alloc(10000L*1024*2);
    unsigned short* Wahh  = (unsigned short*)alloc(512L*1024*2);
    unsigned short* Wahl  = (unsigned short*)alloc(512L*1024*2);
    unsigned short* Wafh  = (unsigned short*)alloc(512L*2048*2);
    unsigned short* Wafl  = (unsigned short*)alloc(512L*2048*2);
    unsigned short* Warh  = (unsigned short*)alloc(3072L*416*2);
    unsigned short* Warl  = (unsigned short*)alloc(3072L*416*2);

    float* ef    = (float*)alloc(10240L*512*4);
    float* base1 = (float*)alloc(4096L*256*4);
    float* Pbuf  = (float*)alloc(5L*4096*256*4);
    float* attrv = Pbuf;                          // temporal overlay

    unsigned short* h1h = (unsigned short*)alloc(256L*1024*2);
    unsigned short* h1l = (unsigned short*)alloc(256L*1024*2);
    unsigned short* h2h = (unsigned short*)alloc(256L*1024*2);
    unsigned short* h2l = (unsigned short*)alloc(256L*1024*2);
    unsigned short* wvh = (unsigned short*)alloc(256L*512*2);
    unsigned short* wvl = (unsigned short*)alloc(256L*512*2);
    unsigned short* vhh = (unsigned short*)alloc(256L*2048*2);
    unsigned short* vhl = (unsigned short*)alloc(256L*2048*2);
    unsigned short* mfh = (unsigned short*)alloc(256L*2048*2);
    unsigned short* mfl = (unsigned short*)alloc(256L*2048*2);
    unsigned short* attsh = (unsigned short*)alloc(256L*416*2);
    unsigned short* attsl = (unsigned short*)alloc(256L*416*2);
    unsigned short* avh = (unsigned short*)alloc(256L*3072*2);
    unsigned short* avl = (unsigned short*)alloc(256L*3072*2);
    float* c1 = (float*)alloc(256L*1024*4);
    float* c2 = (float*)alloc(256L*1024*4);
    float* bihbhh1 = (float*)alloc(4096*4);
    float* bias2   = (float*)alloc(4096*4);
    float* efbias  = (float*)alloc(512*4);

    // ---- one-time precompute ----
    hipMemsetAsync(c1, 0, 256L*1024*4, stream);
    hipMemsetAsync(c2, 0, 256L*1024*4, stream);
    hipMemsetAsync(h1h, 0, 256L*1024*2, stream);   // bf16(0) == 0x0000
    hipMemsetAsync(h1l, 0, 256L*1024*2, stream);

    vec_add_kernel<<<16, 256, 0, stream>>>(l1_bih, l1_bhh, bihbhh1, 4096);
    vec_add_kernel<<<16, 256, 0, stream>>>(l2_bih, l2_bhh, bias2, 4096);
    vec_add_kernel<<<2, 256, 0, stream>>>(attf_b, atth_b, efbias, 512);
    mean_cast<<<2048, 256, 0, stream>>>(feats, mfh, mfl);

    // weight casts outside region R
    cast_slice<<<dim3(4,4096), 256, 0, stream>>>(l1_Wih, W1ph, W1pl, 3584, 0,    1024, 1024, 1536, 0);
    cast_slice<<<dim3(2,4096), 256, 0, stream>>>(l1_Wih, W1ph, W1pl, 3584, 3072, 512,  512,  1536, 1024);
    cast_slice<<<dim3(4,4096), 256, 0, stream>>>(l1_Whh, W1hhh, W1hhl, 1024, 0, 1024, 1024, 1024, 0);
    cast_slice<<<dim3(4,4096), 256, 0, stream>>>(l2_Whh, W2hhh, W2hhl, 1024, 0, 1024, 1024, 1024, 0);
    cast_slice<<<dim3(4,10000), 256, 0, stream>>>(prob_W, Wprh, Wprl, 1024, 0, 1024, 1024, 1024, 0);
    cast_slice<<<dim3(4,512), 256, 0, stream>>>(atth_W, Wahh, Wahl, 1024, 0, 1024, 1024, 1024, 0);
    cast_slice<<<dim3(8,512), 256, 0, stream>>>(attf_W, Wafh, Wafl, 2048, 0, 2048, 2048, 2048, 0);
    cast_slice<<<dim3(2,3072), 256, 0, stream>>>(attr_W, Warh, Warl, 400, 0, 400, 416, 416, 0);
    cast_slice<<<dim3(2,256), 256, 0, stream>>>(atts, attsh, attsl, 400, 0, 400, 416, 416, 0);

    // embedf: ef[(b,t)][a] = featsT @ attf_W.T + (attf_b + atth_b)
    transpose_cast_feats<<<dim3(32,256), 256, 0, stream>>>(feats, fTh, fTl);
    {
        GChunks ch = {};
        ch.c[0] = {Wafh, Wafl, fTh, fTl, 2048, 2048, 2048};
        gemm_mfma<1><<<dim3(4,40,1), 512, 0, stream>>>(ch, ef, efbias, 512, 512L, 0);
    }
    // attr_v = atts @ attr_W.T + attr_b  (K padded 400->416 with zeros)
    {
        GChunks ch = {};
        ch.c[0] = {Warh, Warl, attsh, attsl, 416, 416, 416};
        gemm_mfma<1><<<dim3(24,1,1), 512, 0, stream>>>(ch, attrv, attr_b, 3072, 3072L, 0);
        cast_slice<<<dim3(12,256), 256, 0, stream>>>(attrv, avh, avl, 3072, 0, 3072, 3072, 3072, 0);
    }
    // featsT now dead: overlay W2ih + W1ih-mid into region R
    cast_slice<<<dim3(12,4096), 256, 0, stream>>>(l2_Wih, W2ihh, W2ihl, 3072, 0, 3072, 3072, 3072, 0);
    cast_slice<<<dim3(8,4096), 256, 0, stream>>>(l1_Wih, Wmh, Wml, 3584, 1024, 2048, 2048, 2048, 0);
    // base1[b][4096] = mf @ Wih[:,1024:3072].T + (l1_bih + l1_bhh)
    {
        GChunks ch = {};
        ch.c[0] = {Wmh,        Wml,        mfh,        mfl,        2048, 2048, 1024};
        ch.c[1] = {Wmh + 1024, Wml + 1024, mfh + 1024, mfl + 1024, 2048, 2048, 1024};
        gemm_mfma<0><<<dim3(32,1,2), 512, 0, stream>>>(ch, Pbuf, nullptr, 4096, 4096L, 4096L*256);
        reduce_rows<<<1024, 256, 0, stream>>>(base1, Pbuf, bihbhh1, 2, 4096L*256, 4096*256, 4095);
    }
    // initial lstm2 on attr_v (h2 = 0)
    {
        GChunks ch = {};
        for (int z = 0; z < 3; ++z)
            ch.c[z] = {W2ihh + z*1024, W2ihl + z*1024, avh + z*1024, avl + z*1024, 3072, 3072, 1024};
        gemm_mfma<0><<<dim3(32,1,3), 512, 0, stream>>>(ch, Pbuf, nullptr, 4096, 4096L, 4096L*256);
        lstm_fused<<<1024, 256, 0, stream>>>(Pbuf, 3, 4096L*256, bias2, 2, c2, h2h, h2l);
    }

    // static per-step chunk descriptors (y-merged: weights fetched once)
    GChunks chG1 = {};
    chG1.c[0] = {W1ph,        W1pl,        h2h, h2l, 1536, 1024, 1024};
    chG1.c[1] = {W1ph + 1024, W1pl + 1024, wvh, wvl, 1536, 512,  512};
    chG1.c[2] = {W1hhh,       W1hhl,       h1h, h1l, 1024, 1024, 1024};
    GChunks chEh = {};
    for (int z = 0; z < 8; ++z)
        chEh.c[z] = {Wahh + z*128, Wahl + z*128, h1h + z*128, h1l + z*128, 1024, 1024, 128};
    GChunks chG2 = {};
    chG2.c[0] = {W2ihh,        W2ihl,        h1h,        h1l,        3072, 1024, 1024};
    chG2.c[1] = {W2ihh + 1024, W2ihl + 1024, vhh,        vhl,        3072, 2048, 1024};
    chG2.c[2] = {W2ihh + 2048, W2ihl + 2048, vhh + 1024, vhl + 1024, 3072, 2048, 1024};
    chG2.c[3] = {W2hhh,        W2hhl,        h2h,        h2l,        1024, 1024, 1024};
    GChunks chPr = {};
    chPr.c[0] = {Wprh, Wprl, h2h, h2l, 1024, 1024, 1024};

    for (int s = 0; s < NS_; ++s) {
        wv_gather_cast<<<512, 256, 0, stream>>>(sents, emb, wvh, wvl, s);

        gemm_mfma<0><<<dim3(32,1,3), 512, 0, stream>>>(chG1, Pbuf, nullptr, 4096, 4096L, 4096L*256);
        lstm_fused<<<1024, 256, 0, stream>>>(Pbuf, 3, 4096L*256, base1, 1, c1, h1h, h1l);

        gemm_mfma<0><<<dim3(4,1,8), 512, 0, stream>>>(chEh, Pbuf, nullptr, 512, 512L, 512L*256);
        attention_kernel<<<256, 256, 0, stream>>>(ef, Pbuf, feats, atta_W, atta_b, vhh, vhl);

        gemm_mfma<0><<<dim3(32,1,4), 512, 0, stream>>>(chG2, Pbuf, nullptr, 4096, 4096L, 4096L*256);
        lstm_fused<<<1024, 256, 0, stream>>>(Pbuf, 4, 4096L*256, bias2, 2, c2, h2h, h2l);

        // prob GEMM: single K-chunk, direct write into preds with bias
        gemm_mfma<1><<<dim3(79,1,1), 512, 0, stream>>>(
            chPr, preds + (long)s * V_, prob_b, 10000, (long)NS_ * V_, 0);

        argmax_kernel<<<256, 256, 0, stream>>>(preds, out, s);
    }
}

// Round 3
// 4552.953 us; speedup vs baseline: 1.3719x; 1.3719x over previous
//
#include <hip/hip_runtime.h>
#include <cmath>

#define B_ 256
#define F_ 2048
#define T_ 40
#define V_ 10000
#define L_ 20
#define ATTR_ 400
#define E_ 512
#define H_ 1024
#define A_ 512
#define NS_ 19

typedef float f32x4 __attribute__((ext_vector_type(4)));
typedef short bf16x8 __attribute__((ext_vector_type(8)));

__device__ __forceinline__ float sigm(float x) { return 1.0f / (1.0f + expf(-x)); }

// split-bf16 helpers: x ~= hi + lo, each bf16 (RNE). residual ~2^-18 * |x|
__device__ __forceinline__ unsigned short f2bf(float x) {
    unsigned int u = __float_as_uint(x);
    u += 0x7fffu + ((u >> 16) & 1u);
    return (unsigned short)(u >> 16);
}
__device__ __forceinline__ float bf2f(unsigned short h) {
    return __uint_as_float(((unsigned int)h) << 16);
}
__device__ __forceinline__ void gload16(const void* g, void* l) {
    __builtin_amdgcn_global_load_lds(
        (const __attribute__((address_space(1))) unsigned int*)g,
        (__attribute__((address_space(3))) unsigned int*)l, 16, 0, 0);
}
__device__ __forceinline__ f32x4 mfma16(bf16x8 a, bf16x8 b, f32x4 c) {
    return __builtin_amdgcn_mfma_f32_16x16x32_bf16(a, b, c, 0, 0, 0);
}
// slab-major swizzle: element (m,k) -> slab stream offset (in shorts).
// slab = 1KB = [kg:4][r:16][j:8]; slabs ordered [kblk][mslab].
__device__ __forceinline__ long swz(int m, int k, int mslabs) {
    return ((long)(k >> 5) * mslabs + (m >> 4)) * 512
         + ((k >> 3) & 3) * 128 + (m & 15) * 8 + (k & 7);
}

// ---------------------------------------------------------------------------
// Split-bf16 MFMA GEMM, depth-2 pipelined (counted vmcnt, 3 LDS buffers).
// C[b][m] = sum_k A[m][k]*B[b][k]; A/B stored SLAB-MAJOR (see swz) so every
// global_load_lds stages one contiguous 1KB slab per wave (perfect coalesce,
// linear LDS dest). Tile 128m x 256n, 512 threads (8 waves, 2m x 4n),
// per-wave 64x64 via 4x4 frags of v_mfma_f32_16x16x32_bf16 (hh+hl+lh).
// K-loop: tiles ks, ks+1 in flight; s_waitcnt vmcnt(6) (NOT 0) + raw barrier
// -> each tile's loads get ~2 compute phases to land. Stage of buf (ks+2)%3
// placed after the barrier (all waves done reading it at iter ks-1).
// blockIdx.z: independent K-chunk -> out + z*zstride (DIRECT=0) or direct
// store with bias[m] (DIRECT=1).
// ---------------------------------------------------------------------------
struct GChunk {
    const unsigned short* Ahi; const unsigned short* Alo;
    const unsigned short* Bhi; const unsigned short* Blo;
    long ask, bsk;   // per-kblk slab-stream advance (shorts)
    int kc;
};
struct GChunks { GChunk c[8]; };

template<int DIRECT>
__global__ __launch_bounds__(512) void gemm_mfma(
    GChunks ch, float* __restrict__ out, const float* __restrict__ bias,
    int Mreal, long ldc, long zstride)
{
    const GChunk cc = ch.c[blockIdx.z];
    const int tid  = threadIdx.x;
    const int lane = tid & 63;
    const int w    = tid >> 6;
    const int m0   = blockIdx.x * 128;
    const int n0   = blockIdx.y * 256;

    __shared__ __align__(16) unsigned short lds[3][48][512];

    // 48 slabs/tile: A-hi 0..7, A-lo 8..15, B-hi 16..31, B-lo 32..47.
    // wave w stages slabs w*6 .. w*6+5.
    const unsigned short* gp[6];
    long adv[6];
#pragma unroll
    for (int q = 0; q < 6; ++q) {
        int s = w * 6 + q;
        const unsigned short* base; long off;
        if (s < 16) {
            base = (s & 8) ? cc.Alo : cc.Ahi;
            off = ((long)(m0 >> 4) + (s & 7)) * 512;
            adv[q] = cc.ask;
        } else {
            int t2 = s - 16;
            base = (t2 & 16) ? cc.Blo : cc.Bhi;
            off = ((long)(n0 >> 4) + (t2 & 15)) * 512;
            adv[q] = cc.bsk;
        }
        gp[q] = base + off + lane * 8;
    }

    auto stage = [&](int t) {
#pragma unroll
        for (int q = 0; q < 6; ++q) {
            gload16(gp[q], &lds[t][w * 6 + q][lane * 8]);
            gp[q] += adv[q];
        }
    };

    f32x4 zero4 = {0.f, 0.f, 0.f, 0.f};
    f32x4 acc[4][4];
#pragma unroll
    for (int i = 0; i < 4; ++i)
#pragma unroll
        for (int j = 0; j < 4; ++j) acc[i][j] = zero4;

    const int ms0 = (w >> 2) * 4;
    const int ns0 = (w & 3) * 4;

    const int kst = cc.kc >> 5;
    stage(0);
    if (kst > 1) stage(1);
    for (int ks = 0; ks < kst; ++ks) {
        if (ks + 1 < kst) asm volatile("s_waitcnt vmcnt(6)" ::: "memory");
        else              asm volatile("s_waitcnt vmcnt(0)" ::: "memory");
        __builtin_amdgcn_s_barrier();
        __builtin_amdgcn_sched_barrier(0);
        if (ks + 2 < kst) stage((ks + 2) % 3);
        const unsigned short (*buf)[512] = lds[ks % 3];
        bf16x8 ah[4], al[4], bh[4], bl[4];
#pragma unroll
        for (int i = 0; i < 4; ++i) {
            ah[i] = *(const bf16x8*)&buf[ms0 + i][lane * 8];
            al[i] = *(const bf16x8*)&buf[8 + ms0 + i][lane * 8];
            bh[i] = *(const bf16x8*)&buf[16 + ns0 + i][lane * 8];
            bl[i] = *(const bf16x8*)&buf[32 + ns0 + i][lane * 8];
        }
#pragma unroll
        for (int i = 0; i < 4; ++i)
#pragma unroll
            for (int j = 0; j < 4; ++j) {
                acc[i][j] = mfma16(ah[i], bh[j], acc[i][j]);
                acc[i][j] = mfma16(ah[i], bl[j], acc[i][j]);
                acc[i][j] = mfma16(al[i], bh[j], acc[i][j]);
            }
    }

    const int wm = (w >> 2) * 64;
    const int wn = (w & 3) * 64;
    const int mr = (lane >> 4) * 4;
    const int ncl = lane & 15;
    float* P = DIRECT ? out : out + (long)blockIdx.z * zstride;
#pragma unroll
    for (int i = 0; i < 4; ++i) {
        int mm = m0 + wm + i * 16 + mr;
        if (mm < Mreal) {
            float4 bv = {0.f, 0.f, 0.f, 0.f};
            if (DIRECT && bias) bv = *(const float4*)&bias[mm];
#pragma unroll
            for (int j = 0; j < 4; ++j) {
                int bb = n0 + wn + j * 16 + ncl;
                float4 v;
                v.x = acc[i][j].x + bv.x;
                v.y = acc[i][j].y + bv.y;
                v.z = acc[i][j].z + bv.z;
                v.w = acc[i][j].w + bv.w;
                *(float4*)&P[(long)bb * ldc + mm] = v;
            }
        }
    }
}

// fused split-K reduce + LSTM elementwise.  P layout [z][b][4096] (i|f|g|o).
// bmode 1: base[b][4096]; bmode 2: base[n] broadcast.
// h written as swizzled bf16 hi/lo activation (rows=b, k=n).
__global__ __launch_bounds__(256) void lstm_fused(
    const float* __restrict__ P, int nz, long zstride,
    const float* __restrict__ base, int bmode,
    float* __restrict__ c,
    unsigned short* __restrict__ hhi, unsigned short* __restrict__ hlo)
{
    int idx = blockIdx.x * 256 + threadIdx.x;
    int n = idx & 1023;
    int b = idx >> 10;
    long r = (long)b * 4096 + n;
    float ig = 0.f, fg = 0.f, gg = 0.f, og = 0.f;
    for (int z = 0; z < nz; ++z) {
        const float* p = P + (long)z * zstride + r;
        ig += p[0]; fg += p[1024]; gg += p[2048]; og += p[3072];
    }
    if (bmode == 1) {
        const float* q = base + r;
        ig += q[0]; fg += q[1024]; gg += q[2048]; og += q[3072];
    } else {
        ig += base[n]; fg += base[1024 + n]; gg += base[2048 + n]; og += base[3072 + n];
    }
    float cn = sigm(fg) * c[idx] + sigm(ig) * tanhf(gg);
    c[idx] = cn;
    float hv = sigm(og) * tanhf(cn);
    unsigned short hi = f2bf(hv);
    long o = swz(b, n, 16);
    hhi[o] = hi;
    hlo[o] = f2bf(hv - bf2f(hi));
}

// fused attention: eh split-K reduce -> scores -> softmax -> v_hat (swizzled)
__global__ __launch_bounds__(256) void attention_kernel(
    const float* __restrict__ ef, const float* __restrict__ Pe,
    const float* __restrict__ feats, const float* __restrict__ atta_W,
    const float* __restrict__ atta_b,
    unsigned short* __restrict__ vhhi, unsigned short* __restrict__ vhlo)
{
    __shared__ float eh_s[512], aw_s[512], sc_s[48];
    int b = blockIdx.x, tid = threadIdx.x;
    float e0 = 0.f, e1 = 0.f;
#pragma unroll
    for (int z = 0; z < 8; ++z) {
        const float* p = Pe + (long)z * (512 * 256) + b * 512;
        e0 += p[tid]; e1 += p[tid + 256];
    }
    eh_s[tid] = e0; eh_s[tid + 256] = e1;
    aw_s[tid] = atta_W[tid]; aw_s[tid + 256] = atta_W[tid + 256];
    __syncthreads();
    int w = tid >> 6, lane = tid & 63;
    float ab0 = atta_b[0];
    for (int i = 0; i < 10; ++i) {
        int t = w * 10 + i;
        const float* ep = ef + ((long)b * T_ + t) * A_ + lane * 8;
        float4 e1v = *(const float4*)ep;
        float4 e2v = *(const float4*)(ep + 4);
        int a = lane * 8;
        float s = tanhf(e1v.x + eh_s[a+0]) * aw_s[a+0] + tanhf(e1v.y + eh_s[a+1]) * aw_s[a+1]
                + tanhf(e1v.z + eh_s[a+2]) * aw_s[a+2] + tanhf(e1v.w + eh_s[a+3]) * aw_s[a+3]
                + tanhf(e2v.x + eh_s[a+4]) * aw_s[a+4] + tanhf(e2v.y + eh_s[a+5]) * aw_s[a+5]
                + tanhf(e2v.z + eh_s[a+6]) * aw_s[a+6] + tanhf(e2v.w + eh_s[a+7]) * aw_s[a+7];
#pragma unroll
        for (int o = 32; o > 0; o >>= 1) s += __shfl_down(s, o, 64);
        if (lane == 0) sc_s[t] = s + ab0;
    }
    __syncthreads();
    if (tid < 64) {
        float v = (tid < T_) ? sc_s[tid] : -INFINITY;
        float m = v;
#pragma unroll
        for (int o = 32; o > 0; o >>= 1) m = fmaxf(m, __shfl_down(m, o, 64));
        m = __shfl(m, 0, 64);
        float e = (tid < T_) ? expf(v - m) : 0.f;
        float su = e;
#pragma unroll
        for (int o = 32; o > 0; o >>= 1) su += __shfl_down(su, o, 64);
        su = __shfl(su, 0, 64);
        if (tid < T_) sc_s[tid] = e / su;
    }
    __syncthreads();
    for (int cc = 0; cc < 8; ++cc) {
        int f = cc * 256 + tid;
        const float* fp = feats + ((long)b * F_ + f) * T_;
        float acc = 0.f;
#pragma unroll
        for (int t4 = 0; t4 < 10; ++t4) {
            float4 v = *(const float4*)(fp + t4 * 4);
            acc += sc_s[t4*4+0] * v.x + sc_s[t4*4+1] * v.y
                 + sc_s[t4*4+2] * v.z + sc_s[t4*4+3] * v.w;
        }
        unsigned short hi = f2bf(acc);
        long o = swz(b, f, 16);
        vhhi[o] = hi;
        vhlo[o] = f2bf(acc - bf2f(hi));
    }
}

// out[e] = sum_z P[z*zstride+e] + base[e & mask]
__global__ void reduce_rows(float* __restrict__ out, const float* __restrict__ P,
                            const float* __restrict__ base, int S, long zstride,
                            int n, int mask)
{
    long e = ((long)blockIdx.x * 256 + threadIdx.x) * 4;
    if (e >= n) return;
    float4 s = *(const float4*)&P[e];
    for (int z = 1; z < S; ++z) {
        float4 p = *(const float4*)&P[(long)z * zstride + e];
        s.x += p.x; s.y += p.y; s.z += p.z; s.w += p.w;
    }
    if (base) {
        float4 bv = *(const float4*)&base[e & mask];
        s.x += bv.x; s.y += bv.y; s.z += bv.z; s.w += bv.w;
    }
    *(float4*)&out[e] = s;
}

// cast fp32 row-major [nrows][srcld] -> slab-major bf16 hi/lo (zero-padded).
// grid = kblks*mslabs*2 blocks of 256; dst writes fully coalesced.
__global__ void cast_swz(const float* __restrict__ src,
    unsigned short* __restrict__ dhi, unsigned short* __restrict__ dlo,
    long srcld, int nrows, int ncols, int mslabs)
{
    long g = (long)blockIdx.x * 256 + threadIdx.x;
    int within = (int)(g & 511);
    long slab = g >> 9;
    int kblk = (int)(slab / mslabs);
    int ms = (int)(slab - (long)kblk * mslabs);
    int kg = within >> 7, r = (within >> 3) & 15, j = within & 7;
    int m = ms * 16 + r;
    int k = kblk * 32 + kg * 8 + j;
    float v = (m < nrows && k < ncols) ? src[(long)m * srcld + k] : 0.f;
    unsigned short hi = f2bf(v);
    dhi[g] = hi; dlo[g] = f2bf(v - bf2f(hi));
}

__global__ void mean_cast(const float* __restrict__ feats,
                          unsigned short* __restrict__ mh, unsigned short* __restrict__ ml)
{
    int idx = blockIdx.x * 256 + threadIdx.x;
    const float* p = feats + (long)idx * T_;
    float s = 0.f;
#pragma unroll
    for (int t = 0; t < T_; t += 4) {
        float4 v = *(const float4*)(p + t);
        s += v.x + v.y + v.z + v.w;
    }
    s *= (1.0f / (float)T_);
    unsigned short hi = f2bf(s);
    int b = idx >> 11, f = idx & 2047;
    long o = swz(b, f, 16);
    mh[o] = hi; ml[o] = f2bf(s - bf2f(hi));
}

// feats[b][f][t] -> fT slab-major (rows bt=b*40+t, k=f), row-slab count 640
__global__ __launch_bounds__(256) void transpose_cast_feats(
    const float* __restrict__ feats,
    unsigned short* __restrict__ fh, unsigned short* __restrict__ fl)
{
    __shared__ float tf[2560];
    int b = blockIdx.y, f0 = blockIdx.x * 64;
    const float* src = feats + (long)b * (F_ * T_) + (long)f0 * T_;
#pragma unroll
    for (int q = 0; q < 10; ++q) tf[q * 256 + threadIdx.x] = src[q * 256 + threadIdx.x];
    __syncthreads();
#pragma unroll
    for (int q = 0; q < 10; ++q) {
        int idx = q * 256 + threadIdx.x;
        int t = idx >> 6, fo = idx & 63;
        int f = f0 + fo;
        int bt = b * T_ + t;
        float v = tf[fo * 40 + t];
        unsigned short hi = f2bf(v);
        long o = ((long)(f >> 5) * 640 + (bt >> 4)) * 512
               + ((f >> 3) & 3) * 128 + (bt & 15) * 8 + (f & 7);
        fh[o] = hi; fl[o] = f2bf(v - bf2f(hi));
    }
}

__global__ void wv_gather_cast(const int* __restrict__ sents, const float* __restrict__ emb,
    unsigned short* __restrict__ wh, unsigned short* __restrict__ wl, int s)
{
    int idx = blockIdx.x * 256 + threadIdx.x;   // b*512 + e
    int b = idx >> 9, e = idx & 511;
    int wd = sents[b * L_ + s];
    float v = emb[(long)wd * E_ + e];
    unsigned short hi = f2bf(v);
    long o = swz(b, e, 16);
    wh[o] = hi; wl[o] = f2bf(v - bf2f(hi));
}

__global__ void vec_add_kernel(const float* a, const float* b, float* out, int n)
{
    int i = blockIdx.x * 256 + threadIdx.x;
    if (i < n) out[i] = a[i] + b[i];
}

__global__ __launch_bounds__(256) void argmax_kernel(
    const float* __restrict__ dout_preds, float* __restrict__ outw, int s)
{
    __shared__ float sv[256];
    __shared__ int   si[256];
    int b = blockIdx.x, tid = threadIdx.x;
    const float* row = dout_preds + (long)b * (NS_ * (long)V_) + (long)s * V_;
    float best = -INFINITY; int bi = 0x7fffffff;
    for (int v = tid; v < V_; v += 256) {
        float x = row[v];
        if (x > best) { best = x; bi = v; }
    }
    sv[tid] = best; si[tid] = bi;
    __syncthreads();
    for (int o = 128; o > 0; o >>= 1) {
        if (tid < o) {
            float ov = sv[tid + o]; int oi = si[tid + o];
            if (ov > sv[tid] || (ov == sv[tid] && oi < si[tid])) { sv[tid] = ov; si[tid] = oi; }
        }
        __syncthreads();
    }
    if (tid == 0) outw[b * NS_ + s] = (float)si[0];
}

extern "C" void kernel_launch(void* const* d_in, const int* in_sizes, int n_in,
                              void* d_out, int out_size, void* d_ws, size_t ws_size,
                              hipStream_t stream)
{
    (void)in_sizes; (void)n_in; (void)out_size; (void)ws_size;
    const float* feats  = (const float*)d_in[0];
    const float* atts   = (const float*)d_in[1];
    const int*   sents  = (const int*)d_in[2];
    const float* attr_W = (const float*)d_in[3];
    const float* attr_b = (const float*)d_in[4];
    const float* emb    = (const float*)d_in[5];
    const float* l1_Wih = (const float*)d_in[6];
    const float* l1_Whh = (const float*)d_in[7];
    const float* l1_bih = (const float*)d_in[8];
    const float* l1_bhh = (const float*)d_in[9];
    const float* l2_Wih = (const float*)d_in[10];
    const float* l2_Whh = (const float*)d_in[11];
    const float* l2_bih = (const float*)d_in[12];
    const float* l2_bhh = (const float*)d_in[13];
    const float* prob_W = (const float*)d_in[14];
    const float* prob_b = (const float*)d_in[15];
    const float* attf_W = (const float*)d_in[16];
    const float* attf_b = (const float*)d_in[17];
    const float* atth_W = (const float*)d_in[18];
    const float* atth_b = (const float*)d_in[19];
    const float* atta_W = (const float*)d_in[20];
    const float* atta_b = (const float*)d_in[21];

    float* out = (float*)d_out;
    float* preds = out + B_ * NS_;

    char* pp = (char*)d_ws;
    auto alloc = [&](size_t n) { char* r = pp; pp += (n + 255) & ~(size_t)255; return r; };

    // slab-stream strides (shorts per kblk)
    const long AS256 = 256L * 512;   // 4096-row weights
    const long AS632 = 632L * 512;   // prob_W padded to 10112 rows
    const long AS32  = 32L * 512;    // 512-row weights
    const long AS192 = 192L * 512;   // attr_W (3072 rows)
    const long BS    = 16L * 512;    // all 256-row activations
    const long BS640 = 640L * 512;   // fT (10240 rows)

    // region R: fT (precompute only) overlaid later by W2ih + Wm
    char* R = alloc(83886080UL);
    unsigned short* fTh   = (unsigned short*)R;
    unsigned short* fTl   = (unsigned short*)(R + 41943040UL);
    unsigned short* W2ihh = (unsigned short*)R;
    unsigned short* W2ihl = (unsigned short*)(R + 25165824UL);
    unsigned short* Wmh   = (unsigned short*)(R + 50331648UL);
    unsigned short* Wml   = (unsigned short*)(R + 67108864UL);

    unsigned short* W1ah  = (unsigned short*)alloc(8388608);   // Wih cols [0:1024)
    unsigned short* W1al  = (unsigned short*)alloc(8388608);
    unsigned short* W1wh  = (unsigned short*)alloc(4194304);   // Wih cols [3072:3584)
    unsigned short* W1wl  = (unsigned short*)alloc(4194304);
    unsigned short* W1hhh = (unsigned short*)alloc(8388608);
    unsigned short* W1hhl = (unsigned short*)alloc(8388608);
    unsigned short* W2hhh = (unsigned short*)alloc(8388608);
    unsigned short* W2hhl = (unsigned short*)alloc(8388608);
    unsigned short* Wprh  = (unsigned short*)alloc(20709376);
    unsigned short* Wprl  = (unsigned short*)alloc(20709376);
    unsigned short* Wahh  = (unsigned short*)alloc(1048576);
    unsigned short* Wahl  = (unsigned short*)alloc(1048576);
    unsigned short* Wafh  = (unsigned short*)alloc(2097152);
    unsigned short* Wafl  = (unsigned short*)alloc(2097152);
    unsigned short* Warh  = (unsigned short*)alloc(2555904);
    unsigned short* Warl  = (unsigned short*)alloc(2555904);

    float* ef    = (float*)alloc(10240L*512*4);
    float* base1 = (float*)alloc(4096L*256*4);
    float* Pbuf  = (float*)alloc(7L*4096*256*4);
    float* attrv = Pbuf;                          // temporal overlay

    unsigned short* h1h = (unsigned short*)alloc(524288);
    unsigned short* h1l = (unsigned short*)alloc(524288);
    unsigned short* h2h = (unsigned short*)alloc(524288);
    unsigned short* h2l = (unsigned short*)alloc(524288);
    unsigned short* wvh = (unsigned short*)alloc(262144);
    unsigned short* wvl = (unsigned short*)alloc(262144);
    unsigned short* vhh = (unsigned short*)alloc(1048576);
    unsigned short* vhl = (unsigned short*)alloc(1048576);
    unsigned short* mfh = (unsigned short*)alloc(1048576);
    unsigned short* mfl = (unsigned short*)alloc(1048576);
    unsigned short* attsh = (unsigned short*)alloc(212992);
    unsigned short* attsl = (unsigned short*)alloc(212992);
    unsigned short* avh = (unsigned short*)alloc(1572864);
    unsigned short* avl = (unsigned short*)alloc(1572864);
    float* c1 = (float*)alloc(256L*1024*4);
    float* c2 = (float*)alloc(256L*1024*4);
    float* bihbhh1 = (float*)alloc(4096*4);
    float* bias2   = (float*)alloc(4096*4);
    float* efbias  = (float*)alloc(512*4);

    // ---- one-time precompute ----
    hipMemsetAsync(c1, 0, 256L*1024*4, stream);
    hipMemsetAsync(c2, 0, 256L*1024*4, stream);
    hipMemsetAsync(h1h, 0, 524288, stream);   // swizzled zeros are zeros
    hipMemsetAsync(h1l, 0, 524288, stream);

    vec_add_kernel<<<16, 256, 0, stream>>>(l1_bih, l1_bhh, bihbhh1, 4096);
    vec_add_kernel<<<16, 256, 0, stream>>>(l2_bih, l2_bhh, bias2, 4096);
    vec_add_kernel<<<2, 256, 0, stream>>>(attf_b, atth_b, efbias, 512);
    mean_cast<<<2048, 256, 0, stream>>>(feats, mfh, mfl);

    // weight casts (slab-major)
    cast_swz<<<16384, 256, 0, stream>>>(l1_Wih,        W1ah, W1al, 3584, 4096, 1024, 256);
    cast_swz<<< 8192, 256, 0, stream>>>(l1_Wih + 3072, W1wh, W1wl, 3584, 4096,  512, 256);
    cast_swz<<<16384, 256, 0, stream>>>(l1_Whh, W1hhh, W1hhl, 1024, 4096, 1024, 256);
    cast_swz<<<16384, 256, 0, stream>>>(l2_Whh, W2hhh, W2hhl, 1024, 4096, 1024, 256);
    cast_swz<<<40448, 256, 0, stream>>>(prob_W, Wprh, Wprl, 1024, 10000, 1024, 632);
    cast_swz<<< 2048, 256, 0, stream>>>(atth_W, Wahh, Wahl, 1024, 512, 1024, 32);
    cast_swz<<< 4096, 256, 0, stream>>>(attf_W, Wafh, Wafl, 2048, 512, 2048, 32);
    cast_swz<<< 4992, 256, 0, stream>>>(attr_W, Warh, Warl, 400, 3072, 400, 192);
    cast_swz<<<  416, 256, 0, stream>>>(atts,   attsh, attsl, 400, 256, 400, 16);

    // embedf: ef[(b,t)][a] = fT @ attf_W.T + (attf_b + atth_b)
    transpose_cast_feats<<<dim3(32,256), 256, 0, stream>>>(feats, fTh, fTl);
    {
        GChunks ch = {};
        ch.c[0] = {Wafh, Wafl, fTh, fTl, AS32, BS640, 2048};
        gemm_mfma<1><<<dim3(4,40,1), 512, 0, stream>>>(ch, ef, efbias, 512, 512L, 0);
    }
    // attr_v = atts @ attr_W.T + attr_b  (K padded 400->416)
    {
        GChunks ch = {};
        ch.c[0] = {Warh, Warl, attsh, attsl, AS192, BS, 416};
        gemm_mfma<1><<<dim3(24,1,1), 512, 0, stream>>>(ch, attrv, attr_b, 3072, 3072L, 0);
        cast_swz<<<3072, 256, 0, stream>>>(attrv, avh, avl, 3072, 256, 3072, 16);
    }
    // fT dead: overlay W2ih + Wm into region R
    cast_swz<<<49152, 256, 0, stream>>>(l2_Wih,        W2ihh, W2ihl, 3072, 4096, 3072, 256);
    cast_swz<<<32768, 256, 0, stream>>>(l1_Wih + 1024, Wmh,   Wml,   3584, 4096, 2048, 256);
    // base1[b][4096] = mf @ Wih[:,1024:3072].T + (l1_bih + l1_bhh)
    {
        GChunks ch = {};
        for (int z = 0; z < 2; ++z)
            ch.c[z] = {Wmh + z*32*AS256, Wml + z*32*AS256,
                       mfh + z*32*BS,    mfl + z*32*BS, AS256, BS, 1024};
        gemm_mfma<0><<<dim3(32,1,2), 512, 0, stream>>>(ch, Pbuf, nullptr, 4096, 4096L, 4096L*256);
        reduce_rows<<<1024, 256, 0, stream>>>(base1, Pbuf, bihbhh1, 2, 4096L*256, 4096*256, 4095);
    }
    // initial lstm2 on attr_v (h2 = 0)
    {
        GChunks ch = {};
        for (int z = 0; z < 3; ++z)
            ch.c[z] = {W2ihh + z*32*AS256, W2ihl + z*32*AS256,
                       avh + z*32*BS,      avl + z*32*BS, AS256, BS, 1024};
        gemm_mfma<0><<<dim3(32,1,3), 512, 0, stream>>>(ch, Pbuf, nullptr, 4096, 4096L, 4096L*256);
        lstm_fused<<<1024, 256, 0, stream>>>(Pbuf, 3, 4096L*256, bias2, 2, c2, h2h, h2l);
    }

    // static per-step chunk descriptors
    GChunks chG1 = {};
    chG1.c[0] = {W1ah,              W1al,              h2h,          h2l,          AS256, BS, 512};
    chG1.c[1] = {W1ah + 16*AS256,   W1al + 16*AS256,   h2h + 16*BS,  h2l + 16*BS,  AS256, BS, 512};
    chG1.c[2] = {W1wh,              W1wl,              wvh,          wvl,          AS256, BS, 512};
    chG1.c[3] = {W1hhh,             W1hhl,             h1h,          h1l,          AS256, BS, 512};
    chG1.c[4] = {W1hhh + 16*AS256,  W1hhl + 16*AS256,  h1h + 16*BS,  h1l + 16*BS,  AS256, BS, 512};
    GChunks chEh = {};
    for (int z = 0; z < 8; ++z)
        chEh.c[z] = {Wahh + z*4*AS32, Wahl + z*4*AS32,
                     h1h + z*4*BS,    h1l + z*4*BS, AS32, BS, 128};
    GChunks chG2 = {};
    chG2.c[0] = {W2ihh,             W2ihl,             h1h,          h1l,          AS256, BS, 512};
    chG2.c[1] = {W2ihh + 16*AS256,  W2ihl + 16*AS256,  h1h + 16*BS,  h1l + 16*BS,  AS256, BS, 512};
    chG2.c[2] = {W2ihh + 32*AS256,  W2ihl + 32*AS256,  vhh,          vhl,          AS256, BS, 512};
    chG2.c[3] = {W2ihh + 48*AS256,  W2ihl + 48*AS256,  vhh + 16*BS,  vhl + 16*BS,  AS256, BS, 512};
    chG2.c[4] = {W2ihh + 64*AS256,  W2ihl + 64*AS256,  vhh + 32*BS,  vhl + 32*BS,  AS256, BS, 1024};
    chG2.c[5] = {W2hhh,             W2hhl,             h2h,          h2l,          AS256, BS, 512};
    chG2.c[6] = {W2hhh + 16*AS256,  W2hhl + 16*AS256,  h2h + 16*BS,  h2l + 16*BS,  AS256, BS, 512};
    GChunks chPr = {};
    chPr.c[0] = {Wprh, Wprl, h2h, h2l, AS632, BS, 1024};

    for (int s = 0; s < NS_; ++s) {
        wv_gather_cast<<<512, 256, 0, stream>>>(sents, emb, wvh, wvl, s);

        gemm_mfma<0><<<dim3(32,1,5), 512, 0, stream>>>(chG1, Pbuf, nullptr, 4096, 4096L, 4096L*256);
        lstm_fused<<<1024, 256, 0, stream>>>(Pbuf, 5, 4096L*256, base1, 1, c1, h1h, h1l);

        gemm_mfma<0><<<dim3(4,1,8), 512, 0, stream>>>(chEh, Pbuf, nullptr, 512, 512L, 512L*256);
        attention_kernel<<<256, 256, 0, stream>>>(ef, Pbuf, feats, atta_W, atta_b, vhh, vhl);

        gemm_mfma<0><<<dim3(32,1,7), 512, 0, stream>>>(chG2, Pbuf, nullptr, 4096, 4096L, 4096L*256);
        lstm_fused<<<1024, 256, 0, stream>>>(Pbuf, 7, 4096L*256, bias2, 2, c2, h2h, h2l);

        // prob GEMM: single K-chunk, direct write into preds with bias
        gemm_mfma<1><<<dim3(79,1,1), 512, 0, stream>>>(
            chPr, preds + (long)s * V_, prob_b, 10000, (long)NS_ * V_, 0);

        argmax_kernel<<<256, 256, 0, stream>>>(preds, out, s);
    }
}

// Round 5
// 3723.327 us; speedup vs baseline: 1.6776x; 1.2228x over previous
//
#include <hip/hip_runtime.h>
#include <cmath>

#define B_ 256
#define F_ 2048
#define T_ 40
#define V_ 10000
#define L_ 20
#define ATTR_ 400
#define E_ 512
#define H_ 1024
#define A_ 512
#define NS_ 19

typedef float f32x4 __attribute__((ext_vector_type(4)));
typedef short bf16x8 __attribute__((ext_vector_type(8)));

__device__ __forceinline__ float sigm(float x) { return 1.0f / (1.0f + expf(-x)); }

// split-bf16 helpers: x ~= hi + lo, each bf16 (RNE). residual ~2^-18 * |x|
__device__ __forceinline__ unsigned short f2bf(float x) {
    unsigned int u = __float_as_uint(x);
    u += 0x7fffu + ((u >> 16) & 1u);
    return (unsigned short)(u >> 16);
}
__device__ __forceinline__ float bf2f(unsigned short h) {
    return __uint_as_float(((unsigned int)h) << 16);
}
__device__ __forceinline__ void gload16(const void* g, void* l) {
    __builtin_amdgcn_global_load_lds(
        (const __attribute__((address_space(1))) unsigned int*)g,
        (__attribute__((address_space(3))) unsigned int*)l, 16, 0, 0);
}
__device__ __forceinline__ f32x4 mfma16(bf16x8 a, bf16x8 b, f32x4 c) {
    return __builtin_amdgcn_mfma_f32_16x16x32_bf16(a, b, c, 0, 0, 0);
}
// slab-major swizzle: element (m,k) -> slab stream offset (in shorts).
// slab = 1KB = [kg:4][r:16][j:8]; slabs ordered [kblk][mslab].
__device__ __forceinline__ long swz(int m, int k, int mslabs) {
    return ((long)(k >> 5) * mslabs + (m >> 4)) * 512
         + ((k >> 3) & 3) * 128 + (m & 15) * 8 + (k & 7);
}

// ---------------------------------------------------------------------------
// Tile-list split-bf16 MFMA GEMM, depth-2 pipelined (counted vmcnt, 3 bufs).
// Each chunk = an independent GEMM C[b][m] = sum_k A[m][k]*B[b][k] with its
// own output ptr/ldc/bias/M; chunk owns blockIdx.x range [x0, x0+Mtiles).
// A/B slab-major (see swz): every global_load_lds stages one contiguous 1KB
// slab per wave. Tile 128m x 256n, 512 threads (8 waves 2m x 4n), per-wave
// 64x64 via 4x4 frags of v_mfma_f32_16x16x32_bf16 (hh+hl+lh).
// K-loop: tiles ks,ks+1 in flight; s_waitcnt vmcnt(6) + raw barrier.
// ---------------------------------------------------------------------------
struct GChunk {
    const unsigned short* Ahi; const unsigned short* Alo;
    const unsigned short* Bhi; const unsigned short* Blo;
    float* out; const float* bias;
    long ask, bsk, ldc;
    int kc, x0, Mreal;
};
struct GChunks { GChunk c[8]; };

__global__ __launch_bounds__(512) void gemm_mfma(GChunks ch)
{
    const int bx = blockIdx.x;
    int ci = 0;
#pragma unroll
    for (int i = 1; i < 8; ++i) if (ch.c[i].x0 <= bx) ci = i;
    const GChunk cc = ch.c[ci];
    const int tid  = threadIdx.x;
    const int lane = tid & 63;
    const int w    = tid >> 6;
    const int m0   = (bx - cc.x0) * 128;
    const int n0   = blockIdx.y * 256;

    __shared__ __align__(16) unsigned short lds[3][48][512];

    // 48 slabs/tile: A-hi 0..7, A-lo 8..15, B-hi 16..31, B-lo 32..47.
    const unsigned short* gp[6];
    long adv[6];
#pragma unroll
    for (int q = 0; q < 6; ++q) {
        int s = w * 6 + q;
        const unsigned short* base; long off;
        if (s < 16) {
            base = (s & 8) ? cc.Alo : cc.Ahi;
            off = ((long)(m0 >> 4) + (s & 7)) * 512;
            adv[q] = cc.ask;
        } else {
            int t2 = s - 16;
            base = (t2 & 16) ? cc.Blo : cc.Bhi;
            off = ((long)(n0 >> 4) + (t2 & 15)) * 512;
            adv[q] = cc.bsk;
        }
        gp[q] = base + off + lane * 8;
    }

    auto stage = [&](int t) {
#pragma unroll
        for (int q = 0; q < 6; ++q) {
            gload16(gp[q], &lds[t][w * 6 + q][lane * 8]);
            gp[q] += adv[q];
        }
    };

    f32x4 zero4 = {0.f, 0.f, 0.f, 0.f};
    f32x4 acc[4][4];
#pragma unroll
    for (int i = 0; i < 4; ++i)
#pragma unroll
        for (int j = 0; j < 4; ++j) acc[i][j] = zero4;

    const int ms0 = (w >> 2) * 4;
    const int ns0 = (w & 3) * 4;

    const int kst = cc.kc >> 5;
    stage(0);
    if (kst > 1) stage(1);
    for (int ks = 0; ks < kst; ++ks) {
        if (ks + 1 < kst) asm volatile("s_waitcnt vmcnt(6)" ::: "memory");
        else              asm volatile("s_waitcnt vmcnt(0)" ::: "memory");
        __builtin_amdgcn_s_barrier();
        __builtin_amdgcn_sched_barrier(0);
        if (ks + 2 < kst) stage((ks + 2) % 3);
        const unsigned short (*buf)[512] = lds[ks % 3];
        bf16x8 ah[4], al[4], bh[4], bl[4];
#pragma unroll
        for (int i = 0; i < 4; ++i) {
            ah[i] = *(const bf16x8*)&buf[ms0 + i][lane * 8];
            al[i] = *(const bf16x8*)&buf[8 + ms0 + i][lane * 8];
            bh[i] = *(const bf16x8*)&buf[16 + ns0 + i][lane * 8];
            bl[i] = *(const bf16x8*)&buf[32 + ns0 + i][lane * 8];
        }
#pragma unroll
        for (int i = 0; i < 4; ++i)
#pragma unroll
            for (int j = 0; j < 4; ++j) {
                acc[i][j] = mfma16(ah[i], bh[j], acc[i][j]);
                acc[i][j] = mfma16(ah[i], bl[j], acc[i][j]);
                acc[i][j] = mfma16(al[i], bh[j], acc[i][j]);
            }
    }

    const int wm = (w >> 2) * 64;
    const int wn = (w & 3) * 64;
    const int mr = (lane >> 4) * 4;
    const int ncl = lane & 15;
    float* P = cc.out;
#pragma unroll
    for (int i = 0; i < 4; ++i) {
        int mm = m0 + wm + i * 16 + mr;
        if (mm < cc.Mreal) {
            float4 bv = {0.f, 0.f, 0.f, 0.f};
            if (cc.bias) bv = *(const float4*)&cc.bias[mm];
#pragma unroll
            for (int j = 0; j < 4; ++j) {
                int bb = n0 + wn + j * 16 + ncl;
                float4 v;
                v.x = acc[i][j].x + bv.x;
                v.y = acc[i][j].y + bv.y;
                v.z = acc[i][j].z + bv.z;
                v.w = acc[i][j].w + bv.w;
                *(float4*)&P[(long)bb * cc.ldc + mm] = v;
            }
        }
    }
}

// fused split-K reduce + LSTM elementwise, with optional piggybacked argmax
// blocks (blockIdx.x >= 1024 do argmax of preds row sarg).
// P layout [z][b][4096] (i|f|g|o). bmode 1: base[b][4096]; 2: base[n].
__global__ __launch_bounds__(256) void lstm_fused(
    const float* __restrict__ P, int nz, long zstride,
    const float* __restrict__ base, int bmode,
    float* __restrict__ c,
    unsigned short* __restrict__ hhi, unsigned short* __restrict__ hlo,
    const float* __restrict__ preds_all, float* __restrict__ outw, int sarg)
{
    if (blockIdx.x >= 1024) {
        __shared__ float sv[256];
        __shared__ int   si[256];
        int b = blockIdx.x - 1024, tid = threadIdx.x;
        const float* row = preds_all + (long)b * (NS_ * (long)V_) + (long)sarg * V_;
        float best = -INFINITY; int bi = 0x7fffffff;
        for (int v = tid; v < V_; v += 256) {
            float x = row[v];
            if (x > best) { best = x; bi = v; }
        }
        sv[tid] = best; si[tid] = bi;
        __syncthreads();
        for (int o = 128; o > 0; o >>= 1) {
            if (tid < o) {
                float ov = sv[tid + o]; int oi = si[tid + o];
                if (ov > sv[tid] || (ov == sv[tid] && oi < si[tid])) { sv[tid] = ov; si[tid] = oi; }
            }
            __syncthreads();
        }
        if (tid == 0) outw[b * NS_ + sarg] = (float)si[0];
        return;
    }
    int idx = blockIdx.x * 256 + threadIdx.x;
    int n = idx & 1023;
    int b = idx >> 10;
    long r = (long)b * 4096 + n;
    float ig = 0.f, fg = 0.f, gg = 0.f, og = 0.f;
    for (int z = 0; z < nz; ++z) {
        const float* p = P + (long)z * zstride + r;
        ig += p[0]; fg += p[1024]; gg += p[2048]; og += p[3072];
    }
    if (bmode == 1) {
        const float* q = base + r;
        ig += q[0]; fg += q[1024]; gg += q[2048]; og += q[3072];
    } else {
        ig += base[n]; fg += base[1024 + n]; gg += base[2048 + n]; og += base[3072 + n];
    }
    float cn = sigm(fg) * c[idx] + sigm(ig) * tanhf(gg);
    c[idx] = cn;
    float hv = sigm(og) * tanhf(cn);
    unsigned short hi = f2bf(hv);
    long o = swz(b, n, 16);
    hhi[o] = hi;
    hlo[o] = f2bf(hv - bf2f(hi));
}

// fused attention: eh split-K reduce -> scores -> softmax -> v_hat (swizzled)
__global__ __launch_bounds__(256) void attention_kernel(
    const float* __restrict__ ef, const float* __restrict__ Pe,
    const float* __restrict__ feats, const float* __restrict__ atta_W,
    const float* __restrict__ atta_b,
    unsigned short* __restrict__ vhhi, unsigned short* __restrict__ vhlo)
{
    __shared__ float eh_s[512], aw_s[512], sc_s[48];
    int b = blockIdx.x, tid = threadIdx.x;
    float e0 = 0.f, e1 = 0.f;
#pragma unroll
    for (int z = 0; z < 8; ++z) {
        const float* p = Pe + (long)z * (512 * 256) + b * 512;
        e0 += p[tid]; e1 += p[tid + 256];
    }
    eh_s[tid] = e0; eh_s[tid + 256] = e1;
    aw_s[tid] = atta_W[tid]; aw_s[tid + 256] = atta_W[tid + 256];
    __syncthreads();
    int w = tid >> 6, lane = tid & 63;
    float ab0 = atta_b[0];
    for (int i = 0; i < 10; ++i) {
        int t = w * 10 + i;
        const float* ep = ef + ((long)b * T_ + t) * A_ + lane * 8;
        float4 e1v = *(const float4*)ep;
        float4 e2v = *(const float4*)(ep + 4);
        int a = lane * 8;
        float s = tanhf(e1v.x + eh_s[a+0]) * aw_s[a+0] + tanhf(e1v.y + eh_s[a+1]) * aw_s[a+1]
                + tanhf(e1v.z + eh_s[a+2]) * aw_s[a+2] + tanhf(e1v.w + eh_s[a+3]) * aw_s[a+3]
                + tanhf(e2v.x + eh_s[a+4]) * aw_s[a+4] + tanhf(e2v.y + eh_s[a+5]) * aw_s[a+5]
                + tanhf(e2v.z + eh_s[a+6]) * aw_s[a+6] + tanhf(e2v.w + eh_s[a+7]) * aw_s[a+7];
#pragma unroll
        for (int o = 32; o > 0; o >>= 1) s += __shfl_down(s, o, 64);
        if (lane == 0) sc_s[t] = s + ab0;
    }
    __syncthreads();
    if (tid < 64) {
        float v = (tid < T_) ? sc_s[tid] : -INFINITY;
        float m = v;
#pragma unroll
        for (int o = 32; o > 0; o >>= 1) m = fmaxf(m, __shfl_down(m, o, 64));
        m = __shfl(m, 0, 64);
        float e = (tid < T_) ? expf(v - m) : 0.f;
        float su = e;
#pragma unroll
        for (int o = 32; o > 0; o >>= 1) su += __shfl_down(su, o, 64);
        su = __shfl(su, 0, 64);
        if (tid < T_) sc_s[tid] = e / su;
    }
    __syncthreads();
    for (int cc = 0; cc < 8; ++cc) {
        int f = cc * 256 + tid;
        const float* fp = feats + ((long)b * F_ + f) * T_;
        float acc = 0.f;
#pragma unroll
        for (int t4 = 0; t4 < 10; ++t4) {
            float4 v = *(const float4*)(fp + t4 * 4);
            acc += sc_s[t4*4+0] * v.x + sc_s[t4*4+1] * v.y
                 + sc_s[t4*4+2] * v.z + sc_s[t4*4+3] * v.w;
        }
        unsigned short hi = f2bf(acc);
        long o = swz(b, f, 16);
        vhhi[o] = hi;
        vhlo[o] = f2bf(acc - bf2f(hi));
    }
}

// out[e] = sum_z P[z*zstride+e] + base[e & mask]
__global__ void reduce_rows(float* __restrict__ out, const float* __restrict__ P,
                            const float* __restrict__ base, int S, long zstride,
                            int n, int mask)
{
    long e = ((long)blockIdx.x * 256 + threadIdx.x) * 4;
    if (e >= n) return;
    float4 s = *(const float4*)&P[e];
    for (int z = 1; z < S; ++z) {
        float4 p = *(const float4*)&P[(long)z * zstride + e];
        s.x += p.x; s.y += p.y; s.z += p.z; s.w += p.w;
    }
    if (base) {
        float4 bv = *(const float4*)&base[e & mask];
        s.x += bv.x; s.y += bv.y; s.z += bv.z; s.w += bv.w;
    }
    *(float4*)&out[e] = s;
}

// cast fp32 row-major [nrows][srcld] -> slab-major bf16 hi/lo (zero-padded).
__global__ void cast_swz(const float* __restrict__ src,
    unsigned short* __restrict__ dhi, unsigned short* __restrict__ dlo,
    long srcld, int nrows, int ncols, int mslabs)
{
    long g = (long)blockIdx.x * 256 + threadIdx.x;
    int within = (int)(g & 511);
    long slab = g >> 9;
    int kblk = (int)(slab / mslabs);
    int ms = (int)(slab - (long)kblk * mslabs);
    int kg = within >> 7, r = (within >> 3) & 15, j = within & 7;
    int m = ms * 16 + r;
    int k = kblk * 32 + kg * 8 + j;
    float v = (m < nrows && k < ncols) ? src[(long)m * srcld + k] : 0.f;
    unsigned short hi = f2bf(v);
    dhi[g] = hi; dlo[g] = f2bf(v - bf2f(hi));
}

__global__ void mean_cast(const float* __restrict__ feats,
                          unsigned short* __restrict__ mh, unsigned short* __restrict__ ml)
{
    int idx = blockIdx.x * 256 + threadIdx.x;
    const float* p = feats + (long)idx * T_;
    float s = 0.f;
#pragma unroll
    for (int t = 0; t < T_; t += 4) {
        float4 v = *(const float4*)(p + t);
        s += v.x + v.y + v.z + v.w;
    }
    s *= (1.0f / (float)T_);
    unsigned short hi = f2bf(s);
    int b = idx >> 11, f = idx & 2047;
    long o = swz(b, f, 16);
    mh[o] = hi; ml[o] = f2bf(s - bf2f(hi));
}

// feats[b][f][t] -> fT slab-major (rows bt=b*40+t, k=f), row-slab count 640
__global__ __launch_bounds__(256) void transpose_cast_feats(
    const float* __restrict__ feats,
    unsigned short* __restrict__ fh, unsigned short* __restrict__ fl)
{
    __shared__ float tf[2560];
    int b = blockIdx.y, f0 = blockIdx.x * 64;
    const float* src = feats + (long)b * (F_ * T_) + (long)f0 * T_;
#pragma unroll
    for (int q = 0; q < 10; ++q) tf[q * 256 + threadIdx.x] = src[q * 256 + threadIdx.x];
    __syncthreads();
#pragma unroll
    for (int q = 0; q < 10; ++q) {
        int idx = q * 256 + threadIdx.x;
        int t = idx >> 6, fo = idx & 63;
        int f = f0 + fo;
        int bt = b * T_ + t;
        float v = tf[fo * 40 + t];
        unsigned short hi = f2bf(v);
        long o = ((long)(f >> 5) * 640 + (bt >> 4)) * 512
               + ((f >> 3) & 3) * 128 + (bt & 15) * 8 + (f & 7);
        fh[o] = hi; fl[o] = f2bf(v - bf2f(hi));
    }
}

// all 19 steps of wv = emb[sents[:, s]], swizzled bf16 hi/lo planes
__global__ void wv_gather_cast_all(const int* __restrict__ sents,
    const float* __restrict__ emb,
    unsigned short* __restrict__ wh, unsigned short* __restrict__ wl)
{
    int idx = blockIdx.x * 256 + threadIdx.x;   // b*512 + e
    int s = blockIdx.y;
    int b = idx >> 9, e = idx & 511;
    int wd = sents[b * L_ + s];
    float v = emb[(long)wd * E_ + e];
    unsigned short hi = f2bf(v);
    long o = (long)s * 131072 + swz(b, e, 16);
    wh[o] = hi; wl[o] = f2bf(v - bf2f(hi));
}

__global__ void vec_add_kernel(const float* a, const float* b, float* out, int n)
{
    int i = blockIdx.x * 256 + threadIdx.x;
    if (i < n) out[i] = a[i] + b[i];
}

__global__ __launch_bounds__(256) void argmax_kernel(
    const float* __restrict__ dout_preds, float* __restrict__ outw, int s)
{
    __shared__ float sv[256];
    __shared__ int   si[256];
    int b = blockIdx.x, tid = threadIdx.x;
    const float* row = dout_preds + (long)b * (NS_ * (long)V_) + (long)s * V_;
    float best = -INFINITY; int bi = 0x7fffffff;
    for (int v = tid; v < V_; v += 256) {
        float x = row[v];
        if (x > best) { best = x; bi = v; }
    }
    sv[tid] = best; si[tid] = bi;
    __syncthreads();
    for (int o = 128; o > 0; o >>= 1) {
        if (tid < o) {
            float ov = sv[tid + o]; int oi = si[tid + o];
            if (ov > sv[tid] || (ov == sv[tid] && oi < si[tid])) { sv[tid] = ov; si[tid] = oi; }
        }
        __syncthreads();
    }
    if (tid == 0) outw[b * NS_ + s] = (float)si[0];
}

extern "C" void kernel_launch(void* const* d_in, const int* in_sizes, int n_in,
                              void* d_out, int out_size, void* d_ws, size_t ws_size,
                              hipStream_t stream)
{
    (void)in_sizes; (void)n_in; (void)out_size; (void)ws_size;
    const float* feats  = (const float*)d_in[0];
    const float* atts   = (const float*)d_in[1];
    const int*   sents  = (const int*)d_in[2];
    const float* attr_W = (const float*)d_in[3];
    const float* attr_b = (const float*)d_in[4];
    const float* emb    = (const float*)d_in[5];
    const float* l1_Wih = (const float*)d_in[6];
    const float* l1_Whh = (const float*)d_in[7];
    const float* l1_bih = (const float*)d_in[8];
    const float* l1_bhh = (const float*)d_in[9];
    const float* l2_Wih = (const float*)d_in[10];
    const float* l2_Whh = (const float*)d_in[11];
    const float* l2_bih = (const float*)d_in[12];
    const float* l2_bhh = (const float*)d_in[13];
    const float* prob_W = (const float*)d_in[14];
    const float* prob_b = (const float*)d_in[15];
    const float* attf_W = (const float*)d_in[16];
    const float* attf_b = (const float*)d_in[17];
    const float* atth_W = (const float*)d_in[18];
    const float* atth_b = (const float*)d_in[19];
    const float* atta_W = (const float*)d_in[20];
    const float* atta_b = (const float*)d_in[21];

    float* out = (float*)d_out;
    float* preds = out + B_ * NS_;

    char* pp = (char*)d_ws;
    auto alloc = [&](size_t n) { char* r = pp; pp += (n + 255) & ~(size_t)255; return r; };

    // slab-stream strides (shorts per kblk)
    const long AS256 = 256L * 512;   // 4096-row weights
    const long AS632 = 632L * 512;   // prob_W padded to 10112 rows
    const long AS32  = 32L * 512;    // 512-row weights
    const long AS192 = 192L * 512;   // attr_W (3072 rows)
    const long BS    = 16L * 512;    // all 256-row activations
    const long BS640 = 640L * 512;   // fT (10240 rows)
    const long SLOT  = 4096L * 256;  // Pbuf slot (floats)

    // region R: fT (precompute only) overlaid later by W2ih + Wm
    char* R = alloc(83886080UL);
    unsigned short* fTh   = (unsigned short*)R;
    unsigned short* fTl   = (unsigned short*)(R + 41943040UL);
    unsigned short* W2ihh = (unsigned short*)R;
    unsigned short* W2ihl = (unsigned short*)(R + 25165824UL);
    unsigned short* Wmh   = (unsigned short*)(R + 50331648UL);
    unsigned short* Wml   = (unsigned short*)(R + 67108864UL);

    unsigned short* W1ah  = (unsigned short*)alloc(8388608);   // Wih cols [0:1024)
    unsigned short* W1al  = (unsigned short*)alloc(8388608);
    unsigned short* W1wh  = (unsigned short*)alloc(4194304);   // Wih cols [3072:3584)
    unsigned short* W1wl  = (unsigned short*)alloc(4194304);
    unsigned short* W1hhh = (unsigned short*)alloc(8388608);
    unsigned short* W1hhl = (unsigned short*)alloc(8388608);
    unsigned short* W2hhh = (unsigned short*)alloc(8388608);
    unsigned short* W2hhl = (unsigned short*)alloc(8388608);
    unsigned short* Wprh  = (unsigned short*)alloc(20709376);
    unsigned short* Wprl  = (unsigned short*)alloc(20709376);
    unsigned short* Wahh  = (unsigned short*)alloc(1048576);
    unsigned short* Wahl  = (unsigned short*)alloc(1048576);
    unsigned short* Wafh  = (unsigned short*)alloc(2097152);
    unsigned short* Wafl  = (unsigned short*)alloc(2097152);
    unsigned short* Warh  = (unsigned short*)alloc(2555904);
    unsigned short* Warl  = (unsigned short*)alloc(2555904);

    float* ef    = (float*)alloc(10240L*512*4);
    float* base1 = (float*)alloc(4096L*256*4);
    float* Pbuf  = (float*)alloc(10L*4096*256*4);
    float* ehP   = (float*)alloc(8L*512*256*4);
    float* attrv = Pbuf;                          // temporal overlay

    unsigned short* h1h = (unsigned short*)alloc(524288);
    unsigned short* h1l = (unsigned short*)alloc(524288);
    unsigned short* h2h = (unsigned short*)alloc(524288);
    unsigned short* h2l = (unsigned short*)alloc(524288);
    unsigned short* wvh = (unsigned short*)alloc(19L*131072*2);
    unsigned short* wvl = (unsigned short*)alloc(19L*131072*2);
    unsigned short* vhh = (unsigned short*)alloc(1048576);
    unsigned short* vhl = (unsigned short*)alloc(1048576);
    unsigned short* mfh = (unsigned short*)alloc(1048576);
    unsigned short* mfl = (unsigned short*)alloc(1048576);
    unsigned short* attsh = (unsigned short*)alloc(212992);
    unsigned short* attsl = (unsigned short*)alloc(212992);
    unsigned short* avh = (unsigned short*)alloc(1572864);
    unsigned short* avl = (unsigned short*)alloc(1572864);
    float* c1 = (float*)alloc(256L*1024*4);
    float* c2 = (float*)alloc(256L*1024*4);
    float* bihbhh1 = (float*)alloc(4096*4);
    float* bias2   = (float*)alloc(4096*4);
    float* efbias  = (float*)alloc(512*4);

    auto seal = [](GChunks& g, int used) {
        for (int i = used; i < 8; ++i) g.c[i].x0 = 0x7fffffff;
    };

    // ---- one-time precompute ----
    hipMemsetAsync(c1, 0, 256L*1024*4, stream);
    hipMemsetAsync(c2, 0, 256L*1024*4, stream);
    hipMemsetAsync(h1h, 0, 524288, stream);
    hipMemsetAsync(h1l, 0, 524288, stream);

    vec_add_kernel<<<16, 256, 0, stream>>>(l1_bih, l1_bhh, bihbhh1, 4096);
    vec_add_kernel<<<16, 256, 0, stream>>>(l2_bih, l2_bhh, bias2, 4096);
    vec_add_kernel<<<2, 256, 0, stream>>>(attf_b, atth_b, efbias, 512);
    mean_cast<<<2048, 256, 0, stream>>>(feats, mfh, mfl);
    wv_gather_cast_all<<<dim3(512, 19), 256, 0, stream>>>(sents, emb, wvh, wvl);

    // weight casts (slab-major)
    cast_swz<<<16384, 256, 0, stream>>>(l1_Wih,        W1ah, W1al, 3584, 4096, 1024, 256);
    cast_swz<<< 8192, 256, 0, stream>>>(l1_Wih + 3072, W1wh, W1wl, 3584, 4096,  512, 256);
    cast_swz<<<16384, 256, 0, stream>>>(l1_Whh, W1hhh, W1hhl, 1024, 4096, 1024, 256);
    cast_swz<<<16384, 256, 0, stream>>>(l2_Whh, W2hhh, W2hhl, 1024, 4096, 1024, 256);
    cast_swz<<<40448, 256, 0, stream>>>(prob_W, Wprh, Wprl, 1024, 10000, 1024, 632);
    cast_swz<<< 2048, 256, 0, stream>>>(atth_W, Wahh, Wahl, 1024, 512, 1024, 32);
    cast_swz<<< 4096, 256, 0, stream>>>(attf_W, Wafh, Wafl, 2048, 512, 2048, 32);
    cast_swz<<< 4992, 256, 0, stream>>>(attr_W, Warh, Warl, 400, 3072, 400, 192);
    cast_swz<<<  416, 256, 0, stream>>>(atts,   attsh, attsl, 400, 256, 400, 16);

    // embedf: ef[(b,t)][a] = fT @ attf_W.T + (attf_b + atth_b)
    transpose_cast_feats<<<dim3(32,256), 256, 0, stream>>>(feats, fTh, fTl);
    {
        GChunks g = {};
        g.c[0] = {Wafh, Wafl, fTh, fTl, ef, efbias, AS32, BS640, 512L, 2048, 0, 512};
        seal(g, 1);
        gemm_mfma<<<dim3(4,40), 512, 0, stream>>>(g);
    }
    // attr_v = atts @ attr_W.T + attr_b
    {
        GChunks g = {};
        g.c[0] = {Warh, Warl, attsh, attsl, attrv, attr_b, AS192, BS, 3072L, 416, 0, 3072};
        seal(g, 1);
        gemm_mfma<<<dim3(24,1), 512, 0, stream>>>(g);
        cast_swz<<<3072, 256, 0, stream>>>(attrv, avh, avl, 3072, 256, 3072, 16);
    }
    // fT dead: overlay W2ih + Wm into region R
    cast_swz<<<49152, 256, 0, stream>>>(l2_Wih,        W2ihh, W2ihl, 3072, 4096, 3072, 256);
    cast_swz<<<32768, 256, 0, stream>>>(l1_Wih + 1024, Wmh,   Wml,   3584, 4096, 2048, 256);
    // base1[b][4096] = mf @ Wih[:,1024:3072].T + (l1_bih + l1_bhh)
    {
        GChunks g = {};
        g.c[0] = {Wmh,           Wml,           mfh,        mfl,        Pbuf,        nullptr, AS256, BS, 4096L, 1024,  0, 4096};
        g.c[1] = {Wmh+32*AS256,  Wml+32*AS256,  mfh+32*BS,  mfl+32*BS,  Pbuf+SLOT,   nullptr, AS256, BS, 4096L, 1024, 32, 4096};
        seal(g, 2);
        gemm_mfma<<<dim3(64,1), 512, 0, stream>>>(g);
        reduce_rows<<<1024, 256, 0, stream>>>(base1, Pbuf, bihbhh1, 2, SLOT, 4096*256, 4095);
    }
    // initial lstm2 on attr_v (h2 = 0)
    {
        GChunks g = {};
        for (int z = 0; z < 3; ++z)
            g.c[z] = {W2ihh+z*32*AS256, W2ihl+z*32*AS256, avh+z*32*BS, avl+z*32*BS,
                      Pbuf+z*SLOT, nullptr, AS256, BS, 4096L, 1024, z*32, 4096};
        seal(g, 3);
        gemm_mfma<<<dim3(96,1), 512, 0, stream>>>(g);
        lstm_fused<<<1024, 256, 0, stream>>>(Pbuf, 3, SLOT, bias2, 2, c2, h2h, h2l,
                                             nullptr, nullptr, -1);
    }

    // static dispatch descriptors
    GChunks gEh = {};
    for (int z = 0; z < 8; ++z)
        gEh.c[z] = {Wahh+z*4*AS32, Wahl+z*4*AS32, h1h+z*4*BS, h1l+z*4*BS,
                    ehP + (long)z*512*256, nullptr, AS32, BS, 512L, 128, z*4, 512};
    GChunks gG2 = {};
    {
        const unsigned short* Bh[6] = {h1h, h1h+16*BS, vhh, vhh+16*BS, vhh+32*BS, vhh+48*BS};
        const unsigned short* Bl[6] = {h1l, h1l+16*BS, vhl, vhl+16*BS, vhl+32*BS, vhl+48*BS};
        for (int q = 0; q < 6; ++q)
            gG2.c[q] = {W2ihh+q*16*AS256, W2ihl+q*16*AS256, Bh[q], Bl[q],
                        Pbuf+(4+q)*SLOT, nullptr, AS256, BS, 4096L, 512, q*32, 4096};
        seal(gG2, 6);
    }

    for (int s = 0; s < NS_; ++s) {
        // dispatch 1: G1 (z=3) + W2hh*h2 pre-chunk + prob of step s-1
        GChunks g1 = {};
        g1.c[0] = {W1ah,  W1al,  h2h, h2l, Pbuf,        nullptr, AS256, BS, 4096L, 1024,  0, 4096};
        g1.c[1] = {W1wh,  W1wl,  wvh + (long)s*131072, wvl + (long)s*131072,
                   Pbuf+SLOT,   nullptr, AS256, BS, 4096L,  512, 32, 4096};
        g1.c[2] = {W1hhh, W1hhl, h1h, h1l, Pbuf+2*SLOT, nullptr, AS256, BS, 4096L, 1024, 64, 4096};
        g1.c[3] = {W2hhh, W2hhl, h2h, h2l, Pbuf+3*SLOT, nullptr, AS256, BS, 4096L, 1024, 96, 4096};
        int nblk = 128;
        if (s > 0) {
            g1.c[4] = {Wprh, Wprl, h2h, h2l, preds + (long)(s-1)*V_, prob_b,
                       AS632, BS, (long)NS_*V_, 1024, 128, 10000};
            nblk = 207; seal(g1, 5);
        } else seal(g1, 4);
        gemm_mfma<<<dim3(nblk,1), 512, 0, stream>>>(g1);

        // dispatch 2: lstm1 (+ piggybacked argmax of step s-1)
        lstm_fused<<<(s > 0 ? 1280 : 1024), 256, 0, stream>>>(
            Pbuf, 3, SLOT, base1, 1, c1, h1h, h1l, preds, out, s - 1);

        gemm_mfma<<<dim3(32,1), 512, 0, stream>>>(gEh);
        attention_kernel<<<256, 256, 0, stream>>>(ef, ehP, feats, atta_W, atta_b, vhh, vhl);

        gemm_mfma<<<dim3(192,1), 512, 0, stream>>>(gG2);
        // lstm2: sum W2hh partial (slot 3) + G2 partials (slots 4..9) = 7 slots
        lstm_fused<<<1024, 256, 0, stream>>>(Pbuf + 3*SLOT, 7, SLOT, bias2, 2, c2, h2h, h2l,
                                             nullptr, nullptr, -1);
    }
    // trailing prob + argmax for the last step
    {
        GChunks g = {};
        g.c[0] = {Wprh, Wprl, h2h, h2l, preds + 18L*V_, prob_b,
                  AS632, BS, (long)NS_*V_, 1024, 0, 10000};
        seal(g, 1);
        gemm_mfma<<<dim3(79,1), 512, 0, stream>>>(g);
        argmax_kernel<<<256, 256, 0, stream>>>(preds, out, 18);
    }
}